// Round 6
// baseline (441.473 us; speedup 1.0000x reference)
//
#include <hip/hip_runtime.h>
#include <hip/hip_bf16.h>
#include <stdint.h>

#define NN 100000
#define NE 1600000
#define NF 128
#define SCAN_B ((NN + 255) / 256)   // 391 blocks
#define NGRP 8
#define GSZ (NN / NGRP)             // 12500 exactly
#define NTILE ((NN + 63) / 64)      // 1563 row tiles
#define CAP 220000                  // per-bucket stream capacity (exp ~200K)

typedef __attribute__((ext_vector_type(8))) __bf16 bf16x8;
typedef __attribute__((ext_vector_type(4))) float floatx4;
typedef __attribute__((ext_vector_type(4))) unsigned short ushortx4;
typedef __attribute__((ext_vector_type(8))) unsigned short ushortx8;

static __device__ __forceinline__ unsigned short f2bf(float x) {
    union { float f; unsigned u; } v; v.f = x;
    unsigned r = v.u + 0x7fffu + ((v.u >> 16) & 1u);   // RNE
    return (unsigned short)(r >> 16);
}
static __device__ __forceinline__ float bflo(unsigned w) {
    union { unsigned u; float f; } v; v.u = w << 16; return v.f;
}
static __device__ __forceinline__ float bfhi(unsigned w) {
    union { unsigned u; float f; } v; v.u = w & 0xffff0000u; return v.f;
}

// fp32 -> bf16; plain store so featb allocates in L2/L3 (gathered later)
__global__ void k_convert(const float* __restrict__ s, unsigned short* __restrict__ d, int n4) {
    int i = blockIdx.x * blockDim.x + threadIdx.x;
    if (i < n4) {
        floatx4 f = __builtin_nontemporal_load((const floatx4*)s + i);
        ushortx4 o;
        o.x = f2bf(f.x); o.y = f2bf(f.y); o.z = f2bf(f.z); o.w = f2bf(f.w);
        ((ushortx4*)d)[i] = o;
    }
}

// Build W2t: [n][k] bf16, k in 0..255 = [Wv ; Wu], 16B k-chunks XOR-swizzled
__global__ void k_prep(const float* __restrict__ wv, const float* __restrict__ wu,
                       unsigned short* __restrict__ w2t) {
    int id = blockIdx.x * 256 + threadIdx.x;   // 0..4095
    if (id >= 128 * 32) return;
    int n = id >> 5, kg = id & 31;
    const float* srcm = (kg < 16) ? wv : wu;
    int k0 = (kg & 15) * 8;
    ushortx8 o;
#pragma unroll
    for (int j = 0; j < 8; ++j)
        o[j] = f2bf(srcm[(k0 + j) * 128 + n]);
    int dchunk = n * 32 + (kg ^ (n & 7));
    *(ushortx8*)(w2t + dchunk * 8) = o;
}

// single-pass 8-way binning: pack (dstLocal<<17)|src, LDS-compact per tile,
// flush per-bucket segments coalesced via one global atomic per bucket/tile
__global__ void k_bin(const int* __restrict__ src, const int* __restrict__ dst,
                      unsigned* __restrict__ streams, int* __restrict__ bcur) {
    __shared__ unsigned stage[256];
    __shared__ int hcnt[8], hoff[8], gbase[8];
    int tid = threadIdx.x;
    for (int tile = blockIdx.x; tile < NE / 256; tile += gridDim.x) {
        int i = tile * 256 + tid;               // NE divisible by 256
        int d = __builtin_nontemporal_load(&dst[i]);
        int s = __builtin_nontemporal_load(&src[i]);
        int b = d / GSZ;
        unsigned packed = ((unsigned)(d - b * GSZ) << 17) | (unsigned)s;
        if (tid < 8) hcnt[tid] = 0;
        __syncthreads();
        int r = atomicAdd(&hcnt[b], 1);
        __syncthreads();
        if (tid == 0) {
            int run = 0;
            for (int k = 0; k < 8; ++k) { hoff[k] = run; run += hcnt[k]; }
        }
        if (tid < 8) gbase[tid] = atomicAdd(&bcur[tid], hcnt[tid]);
        __syncthreads();
        stage[hoff[b] + r] = packed;
        __syncthreads();
        unsigned v = stage[tid];
        int bk = 0;
#pragma unroll
        for (int k = 1; k < 8; ++k) bk += (tid >= hoff[k]) ? 1 : 0;
        int pos = gbase[bk] + (tid - hoff[bk]);
        if (pos < CAP) streams[bk * CAP + pos] = v;
    }
}

// per-bucket degree count; bucket pinned to XCD via blockIdx&7 ->
// atomics land in a 50 KB L2-local deg slice, stream read is 800 KB/XCD
__global__ void k_fine_deg(const unsigned* __restrict__ streams,
                           const int* __restrict__ bcur, int* __restrict__ deg) {
    int b = blockIdx.x & 7;
    int len = bcur[b]; if (len > CAP) len = CAP;
    const unsigned* st = streams + b * CAP;
    int base = b * GSZ;
    int stride = (gridDim.x >> 3) * 256;
    for (int i = (blockIdx.x >> 3) * 256 + threadIdx.x; i < len; i += stride) {
        unsigned v = st[i];
        atomicAdd(&deg[base + (int)(v >> 17)], 1);
    }
}

// phase A: per-block exclusive scan of 256 elements; emit block sums
__global__ void k_scan_a(const int* __restrict__ deg, int* __restrict__ offs,
                         int* __restrict__ bsums) {
    __shared__ int sh[256];
    int i = blockIdx.x * 256 + threadIdx.x;
    int v = (i < NN) ? deg[i] : 0;
    sh[threadIdx.x] = v;
    __syncthreads();
    for (int off = 1; off < 256; off <<= 1) {
        int u = (threadIdx.x >= off) ? sh[threadIdx.x - off] : 0;
        __syncthreads();
        sh[threadIdx.x] += u;
        __syncthreads();
    }
    if (i < NN) offs[i] = sh[threadIdx.x] - v;
    if (threadIdx.x == 255) bsums[blockIdx.x] = sh[255];
}

// phase B: single-block exclusive scan of the 391 block sums
__global__ void k_scan_b(int* __restrict__ bsums) {
    __shared__ int sh[512];
    int t = threadIdx.x;
    int v = (t < SCAN_B) ? bsums[t] : 0;
    sh[t] = v;
    __syncthreads();
    for (int off = 1; off < 512; off <<= 1) {
        int u = (t >= off) ? sh[t - off] : 0;
        __syncthreads();
        sh[t] += u;
        __syncthreads();
    }
    if (t < SCAN_B) bsums[t] = sh[t] - v;
    if (t == SCAN_B - 1) bsums[SCAN_B] = sh[t];
}

// phase C: add block prefix, materialize offs + cursor
__global__ void k_scan_c(int* __restrict__ offs, int* __restrict__ cursor,
                         const int* __restrict__ bsums) {
    int i = blockIdx.x * 256 + threadIdx.x;
    if (i < NN) {
        int o = offs[i] + bsums[blockIdx.x];
        offs[i] = o;
        cursor[i] = o;
    }
    if (i == NN - 1) offs[NN] = bsums[SCAN_B];
}

// per-bucket CSR scatter, XCD-pinned: stream (800 KB) + csr slice (800 KB)
// + cursor slice (50 KB) all fit one XCD's 4 MB L2 -> no write amplification
__global__ void k_fine_scatter(const unsigned* __restrict__ streams,
                               const int* __restrict__ bcur, int* __restrict__ cursor,
                               int* __restrict__ csr) {
    int b = blockIdx.x & 7;
    int len = bcur[b]; if (len > CAP) len = CAP;
    const unsigned* st = streams + b * CAP;
    int base = b * GSZ;
    int stride = (gridDim.x >> 3) * 256;
    for (int i = (blockIdx.x >> 3) * 256 + threadIdx.x; i < len; i += stride) {
        unsigned v = st[i];
        int node = base + (int)(v >> 17);
        int p = atomicAdd(&cursor[node], 1);
        csr[p] = (int)(v & 0x1FFFFu);
    }
}

// one wave per node: fp32 accumulate of bf16 feat rows, scale by 1/max(deg,1)
__global__ void k_aggregate(const unsigned short* __restrict__ featb,
                            const int* __restrict__ offs,
                            const int* __restrict__ csr,
                            unsigned short* __restrict__ aggb) {
    int lane = threadIdx.x & 63;
    int node = blockIdx.x * 4 + (threadIdx.x >> 6);
    if (node >= NN) return;
    int s0 = offs[node], s1 = offs[node + 1];
    float a0 = 0.f, a1 = 0.f;
    for (int base = s0; base < s1; base += 64) {
        int e = (base + lane < s1) ? csr[base + lane] : 0;
        int m = s1 - base; if (m > 64) m = 64;
        int j = 0;
        for (; j + 8 <= m; j += 8) {                    // 8 loads in flight
            unsigned w0 = *(const unsigned*)(featb + (size_t)__shfl(e, j + 0, 64) * NF + lane * 2);
            unsigned w1 = *(const unsigned*)(featb + (size_t)__shfl(e, j + 1, 64) * NF + lane * 2);
            unsigned w2 = *(const unsigned*)(featb + (size_t)__shfl(e, j + 2, 64) * NF + lane * 2);
            unsigned w3 = *(const unsigned*)(featb + (size_t)__shfl(e, j + 3, 64) * NF + lane * 2);
            unsigned w4 = *(const unsigned*)(featb + (size_t)__shfl(e, j + 4, 64) * NF + lane * 2);
            unsigned w5 = *(const unsigned*)(featb + (size_t)__shfl(e, j + 5, 64) * NF + lane * 2);
            unsigned w6 = *(const unsigned*)(featb + (size_t)__shfl(e, j + 6, 64) * NF + lane * 2);
            unsigned w7 = *(const unsigned*)(featb + (size_t)__shfl(e, j + 7, 64) * NF + lane * 2);
            a0 += bflo(w0) + bflo(w1) + bflo(w2) + bflo(w3)
                + bflo(w4) + bflo(w5) + bflo(w6) + bflo(w7);
            a1 += bfhi(w0) + bfhi(w1) + bfhi(w2) + bfhi(w3)
                + bfhi(w4) + bfhi(w5) + bfhi(w6) + bfhi(w7);
        }
        for (; j < m; ++j) {
            int nn = __shfl(e, j, 64);
            unsigned w = *(const unsigned*)(featb + (size_t)nn * NF + lane * 2);
            a0 += bflo(w); a1 += bfhi(w);
        }
    }
    int dg = s1 - s0; if (dg < 1) dg = 1;
    float scale = 1.0f / (float)dg;
    unsigned outw = ((unsigned)f2bf(a1 * scale) << 16) | (unsigned)f2bf(a0 * scale);
    *(unsigned*)(aggb + (size_t)node * NF + lane * 2) = outw;
}

// single fused GEMM: out = relu([feat | agg_n] @ W2 + bias), K=256
__global__ __launch_bounds__(256, 2) void k_gemm(
    const unsigned short* __restrict__ featb,
    const unsigned short* __restrict__ aggb,
    const unsigned short* __restrict__ w2t,
    const float* __restrict__ bias,
    float* __restrict__ out) {
    __shared__ unsigned short lds[128 * 256];   // 64 KiB
    for (int i = threadIdx.x; i < 4096; i += 256) {
        ushortx8 w = *(const ushortx8*)(w2t + i * 8);
        *(ushortx8*)(&lds[i * 8]) = w;
    }
    __syncthreads();

    int lane = threadIdx.x & 63;
    int wave = threadIdx.x >> 6;
    int quad = lane >> 4, l15 = lane & 15;

    float bsv[8];
#pragma unroll
    for (int ct = 0; ct < 8; ++ct) bsv[ct] = bias[ct * 16 + l15];

    for (int t = blockIdx.x; t < NTILE; t += gridDim.x) {
        int rb = t * 64 + wave * 16;
        int arow = rb + l15; if (arow > NN - 1) arow = NN - 1;
        const unsigned short* fr = featb + (size_t)arow * NF;
        const unsigned short* ar = aggb + (size_t)arow * NF;
        bf16x8 a[8];
#pragma unroll
        for (int ks = 0; ks < 4; ++ks) {
            a[ks]     = *(const bf16x8*)(fr + ks * 32 + quad * 8);
            a[4 + ks] = *(const bf16x8*)(ar + ks * 32 + quad * 8);
        }
        floatx4 acc[8];
#pragma unroll
        for (int ct = 0; ct < 8; ++ct) acc[ct] = (floatx4){0.f, 0.f, 0.f, 0.f};
#pragma unroll
        for (int ct = 0; ct < 8; ++ct) {
            int n = ct * 16 + l15;
            int rowoff = n << 8;
            int sw = n & 7;
#pragma unroll
            for (int ks = 0; ks < 8; ++ks) {
                int kg = ks * 4 + quad;
                bf16x8 b = *(const bf16x8*)(&lds[rowoff + ((kg ^ sw) << 3)]);
                acc[ct] = __builtin_amdgcn_mfma_f32_16x16x32_bf16(a[ks], b, acc[ct], 0, 0, 0);
            }
        }
#pragma unroll
        for (int ct = 0; ct < 8; ++ct) {
            int col = ct * 16 + l15;
#pragma unroll
            for (int r = 0; r < 4; ++r) {
                int row = rb + quad * 4 + r;
                if (row < NN) {
                    float v = acc[ct][r] + bsv[ct];
                    out[(size_t)row * NF + col] = v > 0.f ? v : 0.f;
                }
            }
        }
    }
}

extern "C" void kernel_launch(void* const* d_in, const int* in_sizes, int n_in,
                              void* d_out, int out_size, void* d_ws, size_t ws_size,
                              hipStream_t stream) {
    const float* feat = (const float*)d_in[0];
    const float* wu   = (const float*)d_in[1];
    const float* wv   = (const float*)d_in[2];
    const float* bias = (const float*)d_in[3];
    const int* src    = (const int*)d_in[4];
    const int* dst    = (const int*)d_in[5];
    float* out        = (float*)d_out;

    char* ws = (char*)d_ws;
    int* deg              = (int*)(ws + 0);                    //   400,000 B
    int* bcur             = (int*)(ws + 400000);               //        32 B
    int* offs             = (int*)(ws + 400128);               //   400,004 B
    int* cursor           = (int*)(ws + 800256);               //   400,000 B
    int* csr              = (int*)(ws + 1200640);              // 6,400,000 B
    unsigned short* featb = (unsigned short*)(ws + 7600640);   // 25,600,000 B
    unsigned short* aggb  = (unsigned short*)(ws + 33200640);  // 25,600,000 B
    unsigned short* w2t   = (unsigned short*)(ws + 58800640);  //    65,536 B
    int* bsums            = (int*)(ws + 58866176);             //     1,568 B
    // bucket streams alias aggb: dead before k_aggregate writes aggb
    unsigned* streams     = (unsigned*)aggb;                   // 8*CAP*4 = 7.04 MB

    (void)hipMemsetAsync(ws, 0, 400032, stream);   // deg + bcur

    k_convert<<<(NN * NF / 4 + 255) / 256, 256, 0, stream>>>(feat, featb, NN * NF / 4);
    k_prep<<<16, 256, 0, stream>>>(wv, wu, w2t);

    k_bin<<<2048, 256, 0, stream>>>(src, dst, streams, bcur);
    k_fine_deg<<<2048, 256, 0, stream>>>(streams, bcur, deg);
    k_scan_a<<<SCAN_B, 256, 0, stream>>>(deg, offs, bsums);
    k_scan_b<<<1, 512, 0, stream>>>(bsums);
    k_scan_c<<<SCAN_B, 256, 0, stream>>>(offs, cursor, bsums);
    k_fine_scatter<<<2048, 256, 0, stream>>>(streams, bcur, cursor, csr);
    k_aggregate<<<(NN + 3) / 4, 256, 0, stream>>>(featb, offs, csr, aggb);
    k_gemm<<<768, 256, 0, stream>>>(featb, aggb, w2t, bias, out);
}

// Round 7
// 384.786 us; speedup vs baseline: 1.1473x; 1.1473x over previous
//
#include <hip/hip_runtime.h>
#include <hip/hip_bf16.h>
#include <stdint.h>

#define NN 100000
#define NE 1600000
#define NF 128
#define SCAN_B ((NN + 255) / 256)   // 391 blocks
#define NGRP 8
#define GSZ (NN / NGRP)             // 12500 exactly
#define NTILE ((NN + 63) / 64)      // 1563 row tiles
#define NB_BIN 1250                 // binning blocks; 1280 edges each

typedef __attribute__((ext_vector_type(8))) __bf16 bf16x8;
typedef __attribute__((ext_vector_type(4))) float floatx4;
typedef __attribute__((ext_vector_type(4))) unsigned short ushortx4;
typedef __attribute__((ext_vector_type(8))) unsigned short ushortx8;

static __device__ __forceinline__ unsigned short f2bf(float x) {
    union { float f; unsigned u; } v; v.f = x;
    unsigned r = v.u + 0x7fffu + ((v.u >> 16) & 1u);   // RNE
    return (unsigned short)(r >> 16);
}
static __device__ __forceinline__ float bflo(unsigned w) {
    union { unsigned u; float f; } v; v.u = w << 16; return v.f;
}
static __device__ __forceinline__ float bfhi(unsigned w) {
    union { unsigned u; float f; } v; v.u = w & 0xffff0000u; return v.f;
}

// fp32 -> bf16
__global__ void k_convert(const float* __restrict__ s, unsigned short* __restrict__ d, int n4) {
    int i = blockIdx.x * blockDim.x + threadIdx.x;
    if (i < n4) {
        floatx4 f = __builtin_nontemporal_load((const floatx4*)s + i);
        ushortx4 o;
        o.x = f2bf(f.x); o.y = f2bf(f.y); o.z = f2bf(f.z); o.w = f2bf(f.w);
        ((ushortx4*)d)[i] = o;
    }
}

// Build W2t: [n][k] bf16, k in 0..255 = [Wv ; Wu], 16B k-chunks XOR-swizzled
__global__ void k_prep(const float* __restrict__ wv, const float* __restrict__ wu,
                       unsigned short* __restrict__ w2t) {
    int id = blockIdx.x * 256 + threadIdx.x;   // 0..4095
    if (id >= 128 * 32) return;
    int n = id >> 5, kg = id & 31;
    const float* srcm = (kg < 16) ? wv : wu;
    int k0 = (kg & 15) * 8;
    ushortx8 o;
#pragma unroll
    for (int j = 0; j < 8; ++j)
        o[j] = f2bf(srcm[(k0 + j) * 128 + n]);
    int dchunk = n * 32 + (kg ^ (n & 7));
    *(ushortx8*)(w2t + dchunk * 8) = o;
}

// pass 1: per-block bucket histogram (LDS atomics only), bucket-major output
__global__ void k_count(const int* __restrict__ dst, int* __restrict__ counts) {
    __shared__ int h[8];
    int tid = threadIdx.x;
    if (tid < 8) h[tid] = 0;
    __syncthreads();
    int base = blockIdx.x * (5 * 256);
#pragma unroll
    for (int t = 0; t < 5; ++t) {
        int d = __builtin_nontemporal_load(&dst[base + t * 256 + tid]);
        atomicAdd(&h[d / GSZ], 1);
    }
    __syncthreads();
    if (tid < 8) counts[tid * NB_BIN + blockIdx.x] = h[tid];
}

// exclusive scan of the 8*NB_BIN=10000 counts (bucket-major) -> segment bases
// also emits bstart[9] bucket boundaries
__global__ void k_scan_counts(int* __restrict__ counts, int* __restrict__ bstart) {
    __shared__ int psum[1024];
    int t = threadIdx.x;
    int v[10];
    int base = t * 10;
    int sum = 0;
#pragma unroll
    for (int j = 0; j < 10; ++j) {
        int idx = base + j;
        v[j] = (idx < 8 * NB_BIN) ? counts[idx] : 0;
        sum += v[j];
    }
    psum[t] = sum;
    __syncthreads();
    for (int off = 1; off < 1024; off <<= 1) {
        int u = (t >= off) ? psum[t - off] : 0;
        __syncthreads();
        psum[t] += u;
        __syncthreads();
    }
    int run = psum[t] - sum;   // exclusive prefix
#pragma unroll
    for (int j = 0; j < 10; ++j) {
        int idx = base + j;
        if (idx < 8 * NB_BIN) {
            counts[idx] = run;
            if (idx % NB_BIN == 0) bstart[idx / NB_BIN] = run;
            run += v[j];
        }
    }
    if (t == 1023) bstart[8] = psum[1023];   // = NE
}

// pass 2: deterministic scatter into bucket-sorted streams; block-private
// LDS cursors (no global atomics), block-disjoint output sub-segments
__global__ void k_binscatter(const int* __restrict__ src, const int* __restrict__ dst,
                             const int* __restrict__ counts, unsigned* __restrict__ streams) {
    __shared__ int scur[8];
    int tid = threadIdx.x;
    if (tid < 8) scur[tid] = counts[tid * NB_BIN + blockIdx.x];
    __syncthreads();
    int base = blockIdx.x * (5 * 256);
#pragma unroll
    for (int t = 0; t < 5; ++t) {
        int i = base + t * 256 + tid;
        int d = __builtin_nontemporal_load(&dst[i]);
        int s = __builtin_nontemporal_load(&src[i]);
        int b = d / GSZ;
        unsigned packed = ((unsigned)(d - b * GSZ) << 17) | (unsigned)s;
        int pos = atomicAdd(&scur[b], 1);
        streams[pos] = packed;
    }
}

// per-bucket degree count; bucket pinned to XCD via blockIdx&7
__global__ void k_fine_deg(const unsigned* __restrict__ streams,
                           const int* __restrict__ bstart, int* __restrict__ deg) {
    int b = blockIdx.x & 7;
    int s = bstart[b], e = bstart[b + 1];
    int basen = b * GSZ;
    int stride = (gridDim.x >> 3) * 256;
    for (int i = s + (blockIdx.x >> 3) * 256 + threadIdx.x; i < e; i += stride) {
        unsigned v = streams[i];
        atomicAdd(&deg[basen + (int)(v >> 17)], 1);
    }
}

// phase A: per-block exclusive scan of 256 elements; emit block sums
__global__ void k_scan_a(const int* __restrict__ deg, int* __restrict__ offs,
                         int* __restrict__ bsums) {
    __shared__ int sh[256];
    int i = blockIdx.x * 256 + threadIdx.x;
    int v = (i < NN) ? deg[i] : 0;
    sh[threadIdx.x] = v;
    __syncthreads();
    for (int off = 1; off < 256; off <<= 1) {
        int u = (threadIdx.x >= off) ? sh[threadIdx.x - off] : 0;
        __syncthreads();
        sh[threadIdx.x] += u;
        __syncthreads();
    }
    if (i < NN) offs[i] = sh[threadIdx.x] - v;
    if (threadIdx.x == 255) bsums[blockIdx.x] = sh[255];
}

// phase B: single-block exclusive scan of the 391 block sums
__global__ void k_scan_b(int* __restrict__ bsums) {
    __shared__ int sh[512];
    int t = threadIdx.x;
    int v = (t < SCAN_B) ? bsums[t] : 0;
    sh[t] = v;
    __syncthreads();
    for (int off = 1; off < 512; off <<= 1) {
        int u = (t >= off) ? sh[t - off] : 0;
        __syncthreads();
        sh[t] += u;
        __syncthreads();
    }
    if (t < SCAN_B) bsums[t] = sh[t] - v;
    if (t == SCAN_B - 1) bsums[SCAN_B] = sh[t];
}

// phase C: add block prefix, materialize offs + cursor
__global__ void k_scan_c(int* __restrict__ offs, int* __restrict__ cursor,
                         const int* __restrict__ bsums) {
    int i = blockIdx.x * 256 + threadIdx.x;
    if (i < NN) {
        int o = offs[i] + bsums[blockIdx.x];
        offs[i] = o;
        cursor[i] = o;
    }
    if (i == NN - 1) offs[NN] = bsums[SCAN_B];
}

// per-bucket CSR scatter, XCD-pinned
__global__ void k_fine_scatter(const unsigned* __restrict__ streams,
                               const int* __restrict__ bstart, int* __restrict__ cursor,
                               int* __restrict__ csr) {
    int b = blockIdx.x & 7;
    int s = bstart[b], e = bstart[b + 1];
    int basen = b * GSZ;
    int stride = (gridDim.x >> 3) * 256;
    for (int i = s + (blockIdx.x >> 3) * 256 + threadIdx.x; i < e; i += stride) {
        unsigned v = streams[i];
        int node = basen + (int)(v >> 17);
        int p = atomicAdd(&cursor[node], 1);
        csr[p] = (int)(v & 0x1FFFFu);
    }
}

// one wave per node: fp32 accumulate of bf16 feat rows, scale by 1/max(deg,1)
__global__ void k_aggregate(const unsigned short* __restrict__ featb,
                            const int* __restrict__ offs,
                            const int* __restrict__ csr,
                            unsigned short* __restrict__ aggb) {
    int lane = threadIdx.x & 63;
    int node = blockIdx.x * 4 + (threadIdx.x >> 6);
    if (node >= NN) return;
    int s0 = offs[node], s1 = offs[node + 1];
    float a0 = 0.f, a1 = 0.f;
    for (int base = s0; base < s1; base += 64) {
        int e = (base + lane < s1) ? csr[base + lane] : 0;
        int m = s1 - base; if (m > 64) m = 64;
        int j = 0;
        for (; j + 8 <= m; j += 8) {                    // 8 loads in flight
            unsigned w0 = *(const unsigned*)(featb + (size_t)__shfl(e, j + 0, 64) * NF + lane * 2);
            unsigned w1 = *(const unsigned*)(featb + (size_t)__shfl(e, j + 1, 64) * NF + lane * 2);
            unsigned w2 = *(const unsigned*)(featb + (size_t)__shfl(e, j + 2, 64) * NF + lane * 2);
            unsigned w3 = *(const unsigned*)(featb + (size_t)__shfl(e, j + 3, 64) * NF + lane * 2);
            unsigned w4 = *(const unsigned*)(featb + (size_t)__shfl(e, j + 4, 64) * NF + lane * 2);
            unsigned w5 = *(const unsigned*)(featb + (size_t)__shfl(e, j + 5, 64) * NF + lane * 2);
            unsigned w6 = *(const unsigned*)(featb + (size_t)__shfl(e, j + 6, 64) * NF + lane * 2);
            unsigned w7 = *(const unsigned*)(featb + (size_t)__shfl(e, j + 7, 64) * NF + lane * 2);
            a0 += bflo(w0) + bflo(w1) + bflo(w2) + bflo(w3)
                + bflo(w4) + bflo(w5) + bflo(w6) + bflo(w7);
            a1 += bfhi(w0) + bfhi(w1) + bfhi(w2) + bfhi(w3)
                + bfhi(w4) + bfhi(w5) + bfhi(w6) + bfhi(w7);
        }
        for (; j < m; ++j) {
            int nn = __shfl(e, j, 64);
            unsigned w = *(const unsigned*)(featb + (size_t)nn * NF + lane * 2);
            a0 += bflo(w); a1 += bfhi(w);
        }
    }
    int dg = s1 - s0; if (dg < 1) dg = 1;
    float scale = 1.0f / (float)dg;
    unsigned outw = ((unsigned)f2bf(a1 * scale) << 16) | (unsigned)f2bf(a0 * scale);
    *(unsigned*)(aggb + (size_t)node * NF + lane * 2) = outw;
}

// single fused GEMM: out = relu([feat | agg_n] @ W2 + bias), K=256
__global__ __launch_bounds__(256, 2) void k_gemm(
    const unsigned short* __restrict__ featb,
    const unsigned short* __restrict__ aggb,
    const unsigned short* __restrict__ w2t,
    const float* __restrict__ bias,
    float* __restrict__ out) {
    __shared__ unsigned short lds[128 * 256];   // 64 KiB
    for (int i = threadIdx.x; i < 4096; i += 256) {
        ushortx8 w = *(const ushortx8*)(w2t + i * 8);
        *(ushortx8*)(&lds[i * 8]) = w;
    }
    __syncthreads();

    int lane = threadIdx.x & 63;
    int wave = threadIdx.x >> 6;
    int quad = lane >> 4, l15 = lane & 15;

    float bsv[8];
#pragma unroll
    for (int ct = 0; ct < 8; ++ct) bsv[ct] = bias[ct * 16 + l15];

    for (int t = blockIdx.x; t < NTILE; t += gridDim.x) {
        int rb = t * 64 + wave * 16;
        int arow = rb + l15; if (arow > NN - 1) arow = NN - 1;
        const unsigned short* fr = featb + (size_t)arow * NF;
        const unsigned short* ar = aggb + (size_t)arow * NF;
        bf16x8 a[8];
#pragma unroll
        for (int ks = 0; ks < 4; ++ks) {
            a[ks]     = *(const bf16x8*)(fr + ks * 32 + quad * 8);
            a[4 + ks] = *(const bf16x8*)(ar + ks * 32 + quad * 8);
        }
        floatx4 acc[8];
#pragma unroll
        for (int ct = 0; ct < 8; ++ct) acc[ct] = (floatx4){0.f, 0.f, 0.f, 0.f};
#pragma unroll
        for (int ct = 0; ct < 8; ++ct) {
            int n = ct * 16 + l15;
            int rowoff = n << 8;
            int sw = n & 7;
#pragma unroll
            for (int ks = 0; ks < 8; ++ks) {
                int kg = ks * 4 + quad;
                bf16x8 b = *(const bf16x8*)(&lds[rowoff + ((kg ^ sw) << 3)]);
                acc[ct] = __builtin_amdgcn_mfma_f32_16x16x32_bf16(a[ks], b, acc[ct], 0, 0, 0);
            }
        }
#pragma unroll
        for (int ct = 0; ct < 8; ++ct) {
            int col = ct * 16 + l15;
#pragma unroll
            for (int r = 0; r < 4; ++r) {
                int row = rb + quad * 4 + r;
                if (row < NN) {
                    float v = acc[ct][r] + bsv[ct];
                    out[(size_t)row * NF + col] = v > 0.f ? v : 0.f;
                }
            }
        }
    }
}

extern "C" void kernel_launch(void* const* d_in, const int* in_sizes, int n_in,
                              void* d_out, int out_size, void* d_ws, size_t ws_size,
                              hipStream_t stream) {
    const float* feat = (const float*)d_in[0];
    const float* wu   = (const float*)d_in[1];
    const float* wv   = (const float*)d_in[2];
    const float* bias = (const float*)d_in[3];
    const int* src    = (const int*)d_in[4];
    const int* dst    = (const int*)d_in[5];
    float* out        = (float*)d_out;

    char* ws = (char*)d_ws;
    int* deg              = (int*)(ws + 0);                    //   400,000 B
    int* bstart           = (int*)(ws + 400000);               //        36 B
    int* offs             = (int*)(ws + 400128);               //   400,004 B
    int* cursor           = (int*)(ws + 800256);               //   400,000 B
    int* csr              = (int*)(ws + 1200640);              // 6,400,000 B
    unsigned short* featb = (unsigned short*)(ws + 7600640);   // 25,600,000 B
    unsigned short* aggb  = (unsigned short*)(ws + 33200640);  // 25,600,000 B
    unsigned short* w2t   = (unsigned short*)(ws + 58800640);  //    65,536 B
    int* bsums            = (int*)(ws + 58866176);             //     1,568 B
    // aliases (disjoint live ranges):
    unsigned* streams     = (unsigned*)aggb;   // NE*4 = 6.4 MB; dead before aggb written
    int* counts           = (int*)csr;         // 10,000 ints; dead before csr written

    (void)hipMemsetAsync(deg, 0, 400000, stream);

    k_convert<<<(NN * NF / 4 + 255) / 256, 256, 0, stream>>>(feat, featb, NN * NF / 4);
    k_prep<<<16, 256, 0, stream>>>(wv, wu, w2t);

    k_count<<<NB_BIN, 256, 0, stream>>>(dst, counts);
    k_scan_counts<<<1, 1024, 0, stream>>>(counts, bstart);
    k_binscatter<<<NB_BIN, 256, 0, stream>>>(src, dst, counts, streams);
    k_fine_deg<<<2048, 256, 0, stream>>>(streams, bstart, deg);
    k_scan_a<<<SCAN_B, 256, 0, stream>>>(deg, offs, bsums);
    k_scan_b<<<1, 512, 0, stream>>>(bsums);
    k_scan_c<<<SCAN_B, 256, 0, stream>>>(offs, cursor, bsums);
    k_fine_scatter<<<2048, 256, 0, stream>>>(streams, bstart, cursor, csr);
    k_aggregate<<<(NN + 3) / 4, 256, 0, stream>>>(featb, offs, csr, aggb);
    k_gemm<<<768, 256, 0, stream>>>(featb, aggb, w2t, bias, out);
}